// Round 3
// baseline (357.948 us; speedup 1.0000x reference)
//
#include <hip/hip_runtime.h>
#include <math.h>

#define G  64
#define NG 2048
#define K  16
#define D  256
#define KD (K*D)             // 4096 floats per graph
#define CHUNK 128            // n-rows per block in project/back kernels

typedef float v4f __attribute__((ext_vector_type(4)));   // clang-native float4

__device__ __forceinline__ int rfl(int v) { return __builtin_amdgcn_readfirstlane(v); }

// ---------------------------------------------------------------------------
// Stage 1: P[g,k,d] += sum_n eigvec[g,n,k] * x[g,n,d]
// grid = G*16 (16 chunks of 128 rows per graph), 256 threads = 4 waves.
// Thread t: float4 column d4 = t&63, row-quarter nq = t>>6 (32 rows each).
// V row address is wave-uniform -> readfirstlane -> scalar s_load (K$),
// no LDS staging. Cross-wave tree reduce in 32KB LDS, then atomicAdd into P.
// ---------------------------------------------------------------------------
__global__ __launch_bounds__(256) void k_project(const float* __restrict__ x,
                                                 const float* __restrict__ eig,
                                                 float* __restrict__ P) {
    __shared__ float red[2 * KD];            // 32 KB
    const int b  = blockIdx.x;
    const int g  = b >> 4, c = b & 15;
    const int n0 = g * NG + c * CHUNK;
    const int t  = threadIdx.x;
    const int d4 = t & 63;
    const int nq = t >> 6;

    float acc[K][4];
#pragma unroll
    for (int k = 0; k < K; ++k)
#pragma unroll
        for (int j = 0; j < 4; ++j) acc[k][j] = 0.f;

    const float4* x4 = (const float4*)x;
#pragma unroll 4
    for (int nn = 0; nn < CHUNK / 4; ++nn) {
        const int un = rfl(n0 + nq * (CHUNK / 4) + nn);   // wave-uniform row
        const float* vr = eig + (size_t)un * K;           // -> s_load_dwordx16
        const float4 xv = x4[(size_t)un * 64 + d4];
#pragma unroll
        for (int k = 0; k < K; ++k) {
            const float vk = vr[k];
            acc[k][0] += vk * xv.x; acc[k][1] += vk * xv.y;
            acc[k][2] += vk * xv.z; acc[k][3] += vk * xv.w;
        }
    }

    // tree reduce across the 4 waves: (2,3) -> (0,1) -> 0
    if (nq >= 2) {
#pragma unroll
        for (int k = 0; k < K; ++k)
            *(float4*)&red[(nq - 2) * KD + k * D + d4 * 4] =
                make_float4(acc[k][0], acc[k][1], acc[k][2], acc[k][3]);
    }
    __syncthreads();
    if (nq < 2) {
#pragma unroll
        for (int k = 0; k < K; ++k) {
            const float4 r = *(const float4*)&red[nq * KD + k * D + d4 * 4];
            acc[k][0] += r.x; acc[k][1] += r.y; acc[k][2] += r.z; acc[k][3] += r.w;
        }
    }
    __syncthreads();
    if (nq == 1) {
#pragma unroll
        for (int k = 0; k < K; ++k)
            *(float4*)&red[k * D + d4 * 4] =
                make_float4(acc[k][0], acc[k][1], acc[k][2], acc[k][3]);
    }
    __syncthreads();
    if (nq == 0) {
        float* Pg = P + (size_t)g * KD;
#pragma unroll
        for (int k = 0; k < K; ++k) {
            const float4 r = *(const float4*)&red[k * D + d4 * 4];
            atomicAdd(Pg + k * D + d4 * 4 + 0, acc[k][0] + r.x);
            atomicAdd(Pg + k * D + d4 * 4 + 1, acc[k][1] + r.y);
            atomicAdd(Pg + k * D + d4 * 4 + 2, acc[k][2] + r.z);
            atomicAdd(Pg + k * D + d4 * 4 + 3, acc[k][3] + r.w);
        }
    }
}

// ---------------------------------------------------------------------------
// Stage 2 (x2): per-graph tiny MLP layer with norm-gated SiLU.
// LAYER==1: in = P, spec_filter, sr, si;  out = y1r, y1i  (gated)
// LAYER==2: in = y1r, y1i; out z = gated_r*fs0 + gated_i*fs1
// grid = G*4 (64 e-columns per block), 256 threads (4 waves = 4 d-quarters).
// ---------------------------------------------------------------------------
template <int LAYER>
__global__ __launch_bounds__(256) void k_mlp(const float* __restrict__ A,
                                             const float* __restrict__ B,
                                             const float* __restrict__ sr,
                                             const float* __restrict__ si,
                                             const float* __restrict__ W,
                                             const float* __restrict__ fs,
                                             float* __restrict__ o0,
                                             float* __restrict__ o1) {
    __shared__ float sXr[KD];                // 16 KB
    __shared__ float sXi[KD];                // 16 KB
    __shared__ float sRed[2 * 4 * K * 64];   // 32 KB  [ri][dq][k][el]
    const int g     = blockIdx.x >> 2;
    const int slice = blockIdx.x & 3;
    const int t     = threadIdx.x;

    if (LAYER == 1) {
        for (int idx = t; idx < KD; idx += 256) {
            const int d = idx & (D - 1);
            const float base = A[(size_t)g * KD + idx] * B[(size_t)g * KD + idx];
            sXr[idx] = base * sr[d];
            sXi[idx] = base * si[d];
        }
    } else {
        const float4* a4 = (const float4*)(A + (size_t)g * KD);
        const float4* b4 = (const float4*)(B + (size_t)g * KD);
        float4* xr4 = (float4*)sXr;
        float4* xi4 = (float4*)sXi;
        for (int idx = t; idx < KD / 4; idx += 256) { xr4[idx] = a4[idx]; xi4[idx] = b4[idx]; }
    }
    __syncthreads();

    const int el = t & 63;                   // local e (wave-lane)
    const int e  = slice * 64 + el;          // output column (row of W)
    const int dq = t >> 6;                   // d-quarter (wave id)

    float pr[K], pi[K];
#pragma unroll
    for (int k = 0; k < K; ++k) { pr[k] = 0.f; pi[k] = 0.f; }

    const float4* w4 = (const float4*)(W + (size_t)e * D);
    for (int ds = dq * 16; ds < dq * 16 + 16; ++ds) {   // 16 float4 = 64 d's
        const float4 w = w4[ds];
        const int d0 = ds * 4;
#pragma unroll
        for (int k = 0; k < K; ++k) {
            const float4 xr = *(const float4*)&sXr[k * D + d0];   // broadcast
            const float4 xi = *(const float4*)&sXi[k * D + d0];
            pr[k] += xr.x * w.x + xr.y * w.y + xr.z * w.z + xr.w * w.w;
            pi[k] += xi.x * w.x + xi.y * w.y + xi.z * w.z + xi.w * w.w;
        }
    }
    __syncthreads();
#pragma unroll
    for (int k = 0; k < K; ++k) {
        sRed[((0 * 4 + dq) * K + k) * 64 + el] = pr[k];
        sRed[((1 * 4 + dq) * K + k) * 64 + el] = pi[k];
    }
    __syncthreads();

    if (t < 64) {                            // wave 0: finish reduce + gate + store
        float hr[K], hi[K];
        float nrm = 0.f;
#pragma unroll
        for (int k = 0; k < K; ++k) {
            float r = 0.f, im = 0.f;
#pragma unroll
            for (int w = 0; w < 4; ++w) {
                r  += sRed[((0 * 4 + w) * K + k) * 64 + t];
                im += sRed[((1 * 4 + w) * K + k) * 64 + t];
            }
            hr[k] = r; hi[k] = im;
            nrm += r * r + im * im;
        }
        const float sg = 1.f / (1.f + expf(-sqrtf(nrm)));
        const int eg = slice * 64 + t;
        if (LAYER == 1) {
#pragma unroll
            for (int k = 0; k < K; ++k) {
                o0[((size_t)g * K + k) * D + eg] = hr[k] * sg;
                o1[((size_t)g * K + k) * D + eg] = hi[k] * sg;
            }
        } else {
            const float f0 = fs[eg * 2], f1 = fs[eg * 2 + 1];
#pragma unroll
            for (int k = 0; k < K; ++k)
                o0[((size_t)g * K + k) * D + eg] = (hr[k] * sg) * f0 + (hi[k] * sg) * f1;
        }
    }
}

// ---------------------------------------------------------------------------
// Stage 3: out[n,d] = x[n,d] + sum_k eigvec[n,k] * z[g,k,d]
// grid = G*16, 256 threads; z slice in registers (16 x float4 / thread),
// V rows via wave-uniform s_load, nontemporal stores keep x L3-resident.
// ---------------------------------------------------------------------------
__global__ __launch_bounds__(256) void k_back(const float* __restrict__ x,
                                              const float* __restrict__ eig,
                                              const float* __restrict__ z,
                                              float* __restrict__ out) {
    const int b  = blockIdx.x;
    const int g  = b >> 4, c = b & 15;
    const int n0 = g * NG + c * CHUNK;
    const int t  = threadIdx.x;
    const int d4 = t & 63;
    const int nq = t >> 6;

    float zr[K][4];
    const float4* z4 = (const float4*)(z + (size_t)g * KD);
#pragma unroll
    for (int k = 0; k < K; ++k) {
        const float4 zv = z4[k * 64 + d4];
        zr[k][0] = zv.x; zr[k][1] = zv.y; zr[k][2] = zv.z; zr[k][3] = zv.w;
    }

    const float4* x4 = (const float4*)x;
    v4f* o4 = (v4f*)out;
#pragma unroll 4
    for (int nn = 0; nn < CHUNK / 4; ++nn) {
        const int un = rfl(n0 + nq * (CHUNK / 4) + nn);   // wave-uniform row
        const float* vr = eig + (size_t)un * K;           // -> s_load_dwordx16
        const size_t idx = (size_t)un * 64 + d4;
        float4 o = x4[idx];
#pragma unroll
        for (int k = 0; k < K; ++k) {
            const float vk = vr[k];
            o.x += vk * zr[k][0]; o.y += vk * zr[k][1];
            o.z += vk * zr[k][2]; o.w += vk * zr[k][3];
        }
        v4f ov; ov.x = o.x; ov.y = o.y; ov.z = o.z; ov.w = o.w;
        __builtin_nontemporal_store(ov, &o4[idx]);
    }
}

// ---------------------------------------------------------------------------
extern "C" void kernel_launch(void* const* d_in, const int* in_sizes, int n_in,
                              void* d_out, int out_size, void* d_ws, size_t ws_size,
                              hipStream_t stream) {
    const float* x    = (const float*)d_in[0];
    const float* eig  = (const float*)d_in[1];
    const float* sr   = (const float*)d_in[2];
    const float* si   = (const float*)d_in[3];
    const float* filt = (const float*)d_in[4];
    const float* W1   = (const float*)d_in[5];
    const float* W2   = (const float*)d_in[6];
    const float* fs   = (const float*)d_in[7];
    float* out = (float*)d_out;

    // workspace layout (3 MB total): P | y1r | y1i ; z reuses P's slot
    float* P   = (float*)d_ws;
    float* y1r = P + (size_t)G * KD;
    float* y1i = y1r + (size_t)G * KD;
    float* z   = P;                          // P dead after k_mlp<1>

    (void)hipMemsetAsync(P, 0, (size_t)G * KD * sizeof(float), stream);
    k_project<<<G * 16, 256, 0, stream>>>(x, eig, P);
    k_mlp<1><<<G * 4, 256, 0, stream>>>(P, filt, sr, si, W1, nullptr, y1r, y1i);
    k_mlp<2><<<G * 4, 256, 0, stream>>>(y1r, y1i, nullptr, nullptr, W2, fs, z, nullptr);
    k_back<<<G * 16, 256, 0, stream>>>(x, eig, z, out);
}

// Round 4
// 339.002 us; speedup vs baseline: 1.0559x; 1.0559x over previous
//
#include <hip/hip_runtime.h>
#include <math.h>

#define G  64
#define NG 2048
#define K  16
#define D  256
#define KD (K*D)               // 4096 floats per graph
#define ROWS 32                // rows per 1-wave block (project/back)
#define NCHUNK (NG/ROWS)       // 64 chunks per graph
#define WPF ((size_t)G * NCHUNK * KD)   // wave-partial floats (16.7M = 64MB)

typedef float v4f __attribute__((ext_vector_type(4)));

// ---------------------------------------------------------------------------
// Stage 1: per-chunk partials WP[b][k][d] = sum_{n in chunk} V[n][k] * x[n][d]
// 4096 blocks x 64 threads (1 wave). V chunk (2KB) in LDS, read as uniform
// broadcast ds_read_b128 (in-order lgkmcnt -> pipelines, unlike s_load).
// No atomics: partials go to scratch carved out of d_out.
// ---------------------------------------------------------------------------
__global__ __launch_bounds__(64) void k_project(const float* __restrict__ x,
                                                const float* __restrict__ eig,
                                                float* __restrict__ WP) {
    __shared__ float sV[ROWS * K];       // 2 KB
    const int b  = blockIdx.x;
    const int g  = b >> 6, c = b & 63;
    const int n0 = g * NG + c * ROWS;
    const int t  = threadIdx.x;          // 0..63

    {   // stage 32 rows x 16 k = 512 floats = 128 float4, coalesced
        const float4* e4 = (const float4*)(eig + (size_t)n0 * K);
        float4* s4 = (float4*)sV;
        s4[t]      = e4[t];
        s4[t + 64] = e4[t + 64];
    }
    __syncthreads();

    float acc[K][4];
#pragma unroll
    for (int k = 0; k < K; ++k)
#pragma unroll
        for (int j = 0; j < 4; ++j) acc[k][j] = 0.f;

    const float4* x4 = (const float4*)x + (size_t)n0 * 64;
#pragma unroll 4
    for (int n = 0; n < ROWS; ++n) {
        const float4 xv = x4[n * 64 + t];
#pragma unroll
        for (int kq = 0; kq < 4; ++kq) {
            const float4 v = *(const float4*)&sV[n * K + kq * 4];  // uniform bcast
            acc[kq*4+0][0] += v.x * xv.x; acc[kq*4+0][1] += v.x * xv.y;
            acc[kq*4+0][2] += v.x * xv.z; acc[kq*4+0][3] += v.x * xv.w;
            acc[kq*4+1][0] += v.y * xv.x; acc[kq*4+1][1] += v.y * xv.y;
            acc[kq*4+1][2] += v.y * xv.z; acc[kq*4+1][3] += v.y * xv.w;
            acc[kq*4+2][0] += v.z * xv.x; acc[kq*4+2][1] += v.z * xv.y;
            acc[kq*4+2][2] += v.z * xv.z; acc[kq*4+2][3] += v.z * xv.w;
            acc[kq*4+3][0] += v.w * xv.x; acc[kq*4+3][1] += v.w * xv.y;
            acc[kq*4+3][2] += v.w * xv.z; acc[kq*4+3][3] += v.w * xv.w;
        }
    }

    float4* wp4 = (float4*)WP + (size_t)b * (KD / 4);
#pragma unroll
    for (int k = 0; k < K; ++k)
        wp4[k * 64 + t] = make_float4(acc[k][0], acc[k][1], acc[k][2], acc[k][3]);
}

// ---------------------------------------------------------------------------
// Stage 1b: Xr/Xi[g][k][d] = (sum_c WP[g,c][k][d]) * filt[g][k][d] * {sr,si}[d]
// grid = G*4 blocks x 256 threads; thread owns one float4 of the graph's KD.
// ---------------------------------------------------------------------------
__global__ __launch_bounds__(256) void k_reduce(const float* __restrict__ WP,
                                                const float* __restrict__ filt,
                                                const float* __restrict__ sr,
                                                const float* __restrict__ si,
                                                float* __restrict__ Xr,
                                                float* __restrict__ Xi) {
    const int b = blockIdx.x;
    const int g = b >> 2, q = b & 3;
    const int f = q * 256 + threadIdx.x;          // float4 index in [0,1024)
    const float4* wp4 = (const float4*)WP + (size_t)g * NCHUNK * (KD / 4);
    float ax = 0.f, ay = 0.f, az = 0.f, aw = 0.f;
#pragma unroll 8
    for (int w = 0; w < NCHUNK; ++w) {
        const float4 p = wp4[(size_t)w * (KD / 4) + f];
        ax += p.x; ay += p.y; az += p.z; aw += p.w;
    }
    const float4 fl = ((const float4*)filt)[(size_t)g * (KD / 4) + f];
    const int d4 = f & 63;
    const float4 s0 = ((const float4*)sr)[d4];
    const float4 s1 = ((const float4*)si)[d4];
    float4 xr, xi;
    xr.x = ax * fl.x * s0.x; xr.y = ay * fl.y * s0.y;
    xr.z = az * fl.z * s0.z; xr.w = aw * fl.w * s0.w;
    xi.x = ax * fl.x * s1.x; xi.y = ay * fl.y * s1.y;
    xi.z = az * fl.z * s1.z; xi.w = aw * fl.w * s1.w;
    ((float4*)Xr)[(size_t)g * (KD / 4) + f] = xr;
    ((float4*)Xi)[(size_t)g * (KD / 4) + f] = xi;
}

// ---------------------------------------------------------------------------
// Stage 2 (x2): h[g,k,e] = sum_d X[g,k,d] * W[e,d]; norm-gated SiLU over k.
// grid = G*4 (block owns 64 e-rows), 256 threads: el = t&63, kq = t>>6.
// W-slice (64KB) staged coalesced into LDS with XOR-(el&7) float4 swizzle ->
// conflict-free strided reads. X read via wave-uniform 16B global loads
// (L1/K$ broadcast; keeps the LDS pipe free). k split across 4 waves.
// ---------------------------------------------------------------------------
template <int LAYER>
__global__ __launch_bounds__(256) void k_mlp(const float* __restrict__ Xr,
                                             const float* __restrict__ Xi,
                                             const float* __restrict__ W,
                                             const float* __restrict__ fs,
                                             float* __restrict__ o0,
                                             float* __restrict__ o1) {
    __shared__ float4 sW[64 * 64];        // 64 KB
    __shared__ float  sRed[4 * 64 * 8];   // 8 KB [kq][el][pr0..3 pi0..3]
    const int b     = blockIdx.x;
    const int g     = b >> 2;
    const int slice = b & 3;
    const int t     = threadIdx.x;

    {   // stage 64 rows of W (slice*64 ..): coalesced float4, swizzled store
        const float4* Wg = (const float4*)W + (size_t)slice * 64 * 64;
#pragma unroll
        for (int it = 0; it < 16; ++it) {
            const int idx = it * 256 + t;        // 0..4095
            const int e = idx >> 6, ds = idx & 63;
            sW[e * 64 + (ds ^ (e & 7))] = Wg[idx];
        }
    }
    __syncthreads();

    const int el = t & 63;
    const int kq = t >> 6;                 // wave-uniform
    const float* xr = Xr + (size_t)g * KD + (kq * 4) * D;
    const float* xi = Xi + (size_t)g * KD + (kq * 4) * D;

    float pr[4] = {0.f, 0.f, 0.f, 0.f};
    float pi[4] = {0.f, 0.f, 0.f, 0.f};
#pragma unroll 4
    for (int ds = 0; ds < 64; ++ds) {
        const float4 w = sW[el * 64 + (ds ^ (el & 7))];
#pragma unroll
        for (int kk = 0; kk < 4; ++kk) {
            const float4 a = *(const float4*)&xr[kk * D + ds * 4];  // uniform
            const float4 c = *(const float4*)&xi[kk * D + ds * 4];  // uniform
            pr[kk] += w.x * a.x + w.y * a.y + w.z * a.z + w.w * a.w;
            pi[kk] += w.x * c.x + w.y * c.y + w.z * c.z + w.w * c.w;
        }
    }

#pragma unroll
    for (int kk = 0; kk < 4; ++kk) {
        sRed[(kq * 64 + el) * 8 + kk]     = pr[kk];
        sRed[(kq * 64 + el) * 8 + 4 + kk] = pi[kk];
    }
    __syncthreads();

    if (t < 64) {
        float hr[K], hi[K];
        float nrm = 0.f;
#pragma unroll
        for (int q2 = 0; q2 < 4; ++q2)
#pragma unroll
            for (int kk = 0; kk < 4; ++kk) {
                const float r  = sRed[(q2 * 64 + t) * 8 + kk];
                const float im = sRed[(q2 * 64 + t) * 8 + 4 + kk];
                hr[q2 * 4 + kk] = r; hi[q2 * 4 + kk] = im;
                nrm += r * r + im * im;
            }
        const float sg = 1.f / (1.f + expf(-sqrtf(nrm)));
        const int e = slice * 64 + t;
        if (LAYER == 1) {
#pragma unroll
            for (int k = 0; k < K; ++k) {
                o0[(size_t)g * KD + k * D + e] = hr[k] * sg;
                o1[(size_t)g * KD + k * D + e] = hi[k] * sg;
            }
        } else {
            const float f0 = fs[e * 2], f1 = fs[e * 2 + 1];
#pragma unroll
            for (int k = 0; k < K; ++k)
                o0[(size_t)g * KD + k * D + e] = (hr[k] * sg) * f0 + (hi[k] * sg) * f1;
        }
    }
}

// ---------------------------------------------------------------------------
// Stage 3: out[n,d] = x[n,d] + sum_k V[n,k] * z[g,k,d]
// 4096 blocks x 64 threads; z slice in 64 VGPRs, V via LDS broadcast reads.
// ---------------------------------------------------------------------------
__global__ __launch_bounds__(64) void k_back(const float* __restrict__ x,
                                             const float* __restrict__ eig,
                                             const float* __restrict__ z,
                                             float* __restrict__ out) {
    __shared__ float sV[ROWS * K];
    const int b  = blockIdx.x;
    const int g  = b >> 6, c = b & 63;
    const int n0 = g * NG + c * ROWS;
    const int t  = threadIdx.x;
    {
        const float4* e4 = (const float4*)(eig + (size_t)n0 * K);
        float4* s4 = (float4*)sV;
        s4[t]      = e4[t];
        s4[t + 64] = e4[t + 64];
    }
    float4 zr[K];
    const float4* z4 = (const float4*)z + (size_t)g * (KD / 4);
#pragma unroll
    for (int k = 0; k < K; ++k) zr[k] = z4[k * 64 + t];
    __syncthreads();

    const float4* x4 = (const float4*)x + (size_t)n0 * 64;
    v4f* o4 = (v4f*)out + (size_t)n0 * 64;
#pragma unroll 4
    for (int n = 0; n < ROWS; ++n) {
        float4 o = x4[n * 64 + t];
#pragma unroll
        for (int kq = 0; kq < 4; ++kq) {
            const float4 v = *(const float4*)&sV[n * K + kq * 4];  // uniform bcast
            o.x += v.x * zr[kq*4+0].x + v.y * zr[kq*4+1].x + v.z * zr[kq*4+2].x + v.w * zr[kq*4+3].x;
            o.y += v.x * zr[kq*4+0].y + v.y * zr[kq*4+1].y + v.z * zr[kq*4+2].y + v.w * zr[kq*4+3].y;
            o.z += v.x * zr[kq*4+0].z + v.y * zr[kq*4+1].z + v.z * zr[kq*4+2].z + v.w * zr[kq*4+3].z;
            o.w += v.x * zr[kq*4+0].w + v.y * zr[kq*4+1].w + v.z * zr[kq*4+2].w + v.w * zr[kq*4+3].w;
        }
        v4f ov; ov.x = o.x; ov.y = o.y; ov.z = o.z; ov.w = o.w;
        __builtin_nontemporal_store(ov, &o4[n * 64 + t]);
    }
}

// ---------------------------------------------------------------------------
extern "C" void kernel_launch(void* const* d_in, const int* in_sizes, int n_in,
                              void* d_out, int out_size, void* d_ws, size_t ws_size,
                              hipStream_t stream) {
    const float* x    = (const float*)d_in[0];
    const float* eig  = (const float*)d_in[1];
    const float* sr   = (const float*)d_in[2];
    const float* si   = (const float*)d_in[3];
    const float* filt = (const float*)d_in[4];
    const float* W1   = (const float*)d_in[5];
    const float* W2   = (const float*)d_in[6];
    const float* fs   = (const float*)d_in[7];
    float* out = (float*)d_out;

    // Scratch carved from d_out (134MB; fully overwritten by k_back at the end):
    //   WP: 4096 x KD = 64MB of wave partials, then Xr/Xi/y1r/y1i (1MB each).
    float* WP  = out;
    float* Xr  = out + WPF;
    float* Xi  = Xr + (size_t)G * KD;
    float* y1r = Xi + (size_t)G * KD;
    float* y1i = y1r + (size_t)G * KD;
    // z is read by k_back while it writes d_out -> must live in ws (ws >= 3MB proven).
    float* z   = (float*)d_ws;

    k_project<<<G * NCHUNK, 64, 0, stream>>>(x, eig, WP);
    k_reduce<<<G * 4, 256, 0, stream>>>(WP, filt, sr, si, Xr, Xi);
    k_mlp<1><<<G * 4, 256, 0, stream>>>(Xr, Xi, W1, nullptr, y1r, y1i);
    k_mlp<2><<<G * 4, 256, 0, stream>>>(y1r, y1i, W2, fs, z, nullptr);
    k_back<<<G * NCHUNK, 64, 0, stream>>>(x, eig, z, out);
}

// Round 5
// 316.631 us; speedup vs baseline: 1.1305x; 1.0707x over previous
//
#include <hip/hip_runtime.h>
#include <math.h>

#define G  64
#define NG 2048
#define K  16
#define D  256
#define KD (K*D)               // 4096 floats per graph
#define PROWS 128              // rows per 4-wave block (project/back)
#define NCHUNK (NG/PROWS)      // 16 chunks per graph
#define WPF ((size_t)G * NCHUNK * KD)   // wave-partial floats (4.2M = 16MB)

typedef float v4f __attribute__((ext_vector_type(4)));

// ---------------------------------------------------------------------------
// Stage 1: WP[g,c][k][d] = sum_{n in 128-row chunk} V[n][k] * x[n][d]
// grid = G*16 blocks x 256T (4 waves). V chunk (8KB) in LDS; wave nq handles
// 32 rows; cross-wave tree reduce in 32KB LDS; block writes one 16KB partial.
// ---------------------------------------------------------------------------
__global__ __launch_bounds__(256) void k_project(const float* __restrict__ x,
                                                 const float* __restrict__ eig,
                                                 float* __restrict__ WP) {
    __shared__ float sV[PROWS * K];      // 8 KB
    __shared__ float red[2 * KD];        // 32 KB
    const int b  = blockIdx.x;
    const int g  = b >> 4, c = b & 15;
    const int n0 = g * NG + c * PROWS;
    const int t  = threadIdx.x;
    const int d4 = t & 63;
    const int nq = t >> 6;

    {   // stage 128 rows x 16 k = 2048 floats = 512 float4, coalesced
        const float4* e4 = (const float4*)(eig + (size_t)n0 * K);
        float4* s4 = (float4*)sV;
        s4[t]       = e4[t];
        s4[t + 256] = e4[t + 256];
    }
    __syncthreads();

    float acc[K][4];
#pragma unroll
    for (int k = 0; k < K; ++k)
#pragma unroll
        for (int j = 0; j < 4; ++j) acc[k][j] = 0.f;

    const float4* x4 = (const float4*)x + ((size_t)n0 + nq * 32) * 64;
    const float* vbase = sV + nq * 32 * K;
#pragma unroll 4
    for (int n = 0; n < 32; ++n) {
        const float4 xv = x4[n * 64 + d4];
#pragma unroll
        for (int kq = 0; kq < 4; ++kq) {
            const float4 v = *(const float4*)&vbase[n * K + kq * 4];  // bcast
            acc[kq*4+0][0] += v.x * xv.x; acc[kq*4+0][1] += v.x * xv.y;
            acc[kq*4+0][2] += v.x * xv.z; acc[kq*4+0][3] += v.x * xv.w;
            acc[kq*4+1][0] += v.y * xv.x; acc[kq*4+1][1] += v.y * xv.y;
            acc[kq*4+1][2] += v.y * xv.z; acc[kq*4+1][3] += v.y * xv.w;
            acc[kq*4+2][0] += v.z * xv.x; acc[kq*4+2][1] += v.z * xv.y;
            acc[kq*4+2][2] += v.z * xv.z; acc[kq*4+2][3] += v.z * xv.w;
            acc[kq*4+3][0] += v.w * xv.x; acc[kq*4+3][1] += v.w * xv.y;
            acc[kq*4+3][2] += v.w * xv.z; acc[kq*4+3][3] += v.w * xv.w;
        }
    }

    // tree reduce: (2,3) -> (0,1) -> 0
    if (nq >= 2) {
#pragma unroll
        for (int k = 0; k < K; ++k)
            *(float4*)&red[(nq - 2) * KD + k * D + d4 * 4] =
                make_float4(acc[k][0], acc[k][1], acc[k][2], acc[k][3]);
    }
    __syncthreads();
    if (nq < 2) {
#pragma unroll
        for (int k = 0; k < K; ++k) {
            const float4 r = *(const float4*)&red[nq * KD + k * D + d4 * 4];
            acc[k][0] += r.x; acc[k][1] += r.y; acc[k][2] += r.z; acc[k][3] += r.w;
        }
    }
    __syncthreads();
    if (nq == 1) {
#pragma unroll
        for (int k = 0; k < K; ++k)
            *(float4*)&red[k * D + d4 * 4] =
                make_float4(acc[k][0], acc[k][1], acc[k][2], acc[k][3]);
    }
    __syncthreads();
    if (nq == 0) {
        float4* wp4 = (float4*)WP + (size_t)b * (KD / 4);
#pragma unroll
        for (int k = 0; k < K; ++k) {
            const float4 r = *(const float4*)&red[k * D + d4 * 4];
            wp4[k * 64 + d4] = make_float4(acc[k][0] + r.x, acc[k][1] + r.y,
                                           acc[k][2] + r.z, acc[k][3] + r.w);
        }
    }
}

// ---------------------------------------------------------------------------
// Stage 1b: Xr/Xi[g][k][d] = (sum_c WP[g,c][k][d]) * filt[g][k][d] * {sr,si}[d]
// grid = G*4 x 256T; thread owns one float4 of the graph's KD.
// ---------------------------------------------------------------------------
__global__ __launch_bounds__(256) void k_reduce(const float* __restrict__ WP,
                                                const float* __restrict__ filt,
                                                const float* __restrict__ sr,
                                                const float* __restrict__ si,
                                                float* __restrict__ Xr,
                                                float* __restrict__ Xi) {
    const int b = blockIdx.x;
    const int g = b >> 2, q = b & 3;
    const int f = q * 256 + threadIdx.x;          // float4 index in [0,1024)
    const float4* wp4 = (const float4*)WP + (size_t)g * NCHUNK * (KD / 4);
    float ax = 0.f, ay = 0.f, az = 0.f, aw = 0.f;
#pragma unroll
    for (int w = 0; w < NCHUNK; ++w) {
        const float4 p = wp4[(size_t)w * (KD / 4) + f];
        ax += p.x; ay += p.y; az += p.z; aw += p.w;
    }
    const float4 fl = ((const float4*)filt)[(size_t)g * (KD / 4) + f];
    const int d4 = f & 63;
    const float4 s0 = ((const float4*)sr)[d4];
    const float4 s1 = ((const float4*)si)[d4];
    float4 xr, xi;
    xr.x = ax * fl.x * s0.x; xr.y = ay * fl.y * s0.y;
    xr.z = az * fl.z * s0.z; xr.w = aw * fl.w * s0.w;
    xi.x = ax * fl.x * s1.x; xi.y = ay * fl.y * s1.y;
    xi.z = az * fl.z * s1.z; xi.w = aw * fl.w * s1.w;
    ((float4*)Xr)[(size_t)g * (KD / 4) + f] = xr;
    ((float4*)Xi)[(size_t)g * (KD / 4) + f] = xi;
}

// ---------------------------------------------------------------------------
// Stage 2 (x2): h[g,k,e] = sum_d X[g,k,d] * W[e,d]; norm-gated SiLU over k.
// grid = G*8 (block owns 32 e-rows), 256T: el=t&31 (e), kg=t>>5 (2 k's each).
// Each thread computes its COMPLETE (e, 2k) dot over all 256 d.
// W slice (32KB) LDS-staged, XOR-swizzled. Only the scalar |h|^2 partial
// crosses threads (8-way LDS reduce) for the gate.
// ---------------------------------------------------------------------------
template <int LAYER>
__global__ __launch_bounds__(256) void k_mlp(const float* __restrict__ Ar,
                                             const float* __restrict__ Ai,
                                             const float* __restrict__ W,
                                             const float* __restrict__ fs,
                                             float* __restrict__ o0,
                                             float* __restrict__ o1) {
    __shared__ float4 sW[32 * 64];        // 32 KB
    __shared__ float  sNrm[8 * 32];
    __shared__ float  sSg[32];
    const int b     = blockIdx.x;
    const int g     = b >> 3;
    const int slice = b & 7;
    const int t     = threadIdx.x;

    {   // stage rows [slice*32, slice*32+32) of W, coalesced, swizzled
        const float4* Wg = (const float4*)W + (size_t)slice * 32 * 64;
#pragma unroll
        for (int it = 0; it < 8; ++it) {
            const int idx = it * 256 + t;        // 0..2047
            const int e = idx >> 6, ds = idx & 63;
            sW[e * 64 + (ds ^ (e & 7))] = Wg[idx];
        }
    }
    __syncthreads();

    const int el = t & 31;
    const int kg = t >> 5;                 // 0..7, owns k = 2kg, 2kg+1
    const int e  = slice * 32 + el;
    const float* ar = Ar + (size_t)g * KD + (kg * 2) * D;
    const float* ai = Ai + (size_t)g * KD + (kg * 2) * D;

    float pr0 = 0.f, pr1 = 0.f, pi0 = 0.f, pi1 = 0.f;
#pragma unroll 8
    for (int ds = 0; ds < 64; ++ds) {
        const float4 w  = sW[el * 64 + (ds ^ (el & 7))];
        const float4 a0 = *(const float4*)&ar[ds * 4];
        const float4 a1 = *(const float4*)&ar[D + ds * 4];
        const float4 c0 = *(const float4*)&ai[ds * 4];
        const float4 c1 = *(const float4*)&ai[D + ds * 4];
        pr0 += w.x * a0.x + w.y * a0.y + w.z * a0.z + w.w * a0.w;
        pr1 += w.x * a1.x + w.y * a1.y + w.z * a1.z + w.w * a1.w;
        pi0 += w.x * c0.x + w.y * c0.y + w.z * c0.z + w.w * c0.w;
        pi1 += w.x * c1.x + w.y * c1.y + w.z * c1.z + w.w * c1.w;
    }

    sNrm[kg * 32 + el] = pr0 * pr0 + pi0 * pi0 + pr1 * pr1 + pi1 * pi1;
    __syncthreads();
    if (t < 32) {
        float nrm = 0.f;
#pragma unroll
        for (int w = 0; w < 8; ++w) nrm += sNrm[w * 32 + t];
        sSg[t] = 1.f / (1.f + expf(-sqrtf(nrm)));
    }
    __syncthreads();
    const float sg = sSg[el];

    float* base0 = o0 + (size_t)g * KD + (kg * 2) * D + e;
    if (LAYER == 1) {
        float* base1 = o1 + (size_t)g * KD + (kg * 2) * D + e;
        base0[0] = pr0 * sg; base0[D] = pr1 * sg;
        base1[0] = pi0 * sg; base1[D] = pi1 * sg;
    } else {
        const float f0 = fs[e * 2], f1 = fs[e * 2 + 1];
        base0[0] = (pr0 * f0 + pi0 * f1) * sg;
        base0[D] = (pr1 * f0 + pi1 * f1) * sg;
    }
}

// ---------------------------------------------------------------------------
// Stage 3: out[n,d] = x[n,d] + sum_k V[n,k] * z[g,k,d]
// grid = G*16 x 256T (4 waves, 128 rows); z slice in 16 float4 regs,
// V via LDS broadcast reads, nontemporal output stores.
// ---------------------------------------------------------------------------
__global__ __launch_bounds__(256) void k_back(const float* __restrict__ x,
                                              const float* __restrict__ eig,
                                              const float* __restrict__ z,
                                              float* __restrict__ out) {
    __shared__ float sV[PROWS * K];      // 8 KB
    const int b  = blockIdx.x;
    const int g  = b >> 4, c = b & 15;
    const int n0 = g * NG + c * PROWS;
    const int t  = threadIdx.x;
    const int d4 = t & 63;
    const int nq = t >> 6;
    {
        const float4* e4 = (const float4*)(eig + (size_t)n0 * K);
        float4* s4 = (float4*)sV;
        s4[t]       = e4[t];
        s4[t + 256] = e4[t + 256];
    }
    float4 zr[K];
    const float4* z4 = (const float4*)z + (size_t)g * (KD / 4);
#pragma unroll
    for (int k = 0; k < K; ++k) zr[k] = z4[k * 64 + d4];
    __syncthreads();

    const float4* x4 = (const float4*)x + ((size_t)n0 + nq * 32) * 64;
    v4f* o4 = (v4f*)out + ((size_t)n0 + nq * 32) * 64;
    const float* vbase = sV + nq * 32 * K;
#pragma unroll 4
    for (int n = 0; n < 32; ++n) {
        float4 o = x4[n * 64 + d4];
#pragma unroll
        for (int kq = 0; kq < 4; ++kq) {
            const float4 v = *(const float4*)&vbase[n * K + kq * 4];  // bcast
            o.x += v.x * zr[kq*4+0].x + v.y * zr[kq*4+1].x + v.z * zr[kq*4+2].x + v.w * zr[kq*4+3].x;
            o.y += v.x * zr[kq*4+0].y + v.y * zr[kq*4+1].y + v.z * zr[kq*4+2].y + v.w * zr[kq*4+3].y;
            o.z += v.x * zr[kq*4+0].z + v.y * zr[kq*4+1].z + v.z * zr[kq*4+2].z + v.w * zr[kq*4+3].z;
            o.w += v.x * zr[kq*4+0].w + v.y * zr[kq*4+1].w + v.z * zr[kq*4+2].w + v.w * zr[kq*4+3].w;
        }
        v4f ov; ov.x = o.x; ov.y = o.y; ov.z = o.z; ov.w = o.w;
        __builtin_nontemporal_store(ov, &o4[n * 64 + d4]);
    }
}

// ---------------------------------------------------------------------------
extern "C" void kernel_launch(void* const* d_in, const int* in_sizes, int n_in,
                              void* d_out, int out_size, void* d_ws, size_t ws_size,
                              hipStream_t stream) {
    const float* x    = (const float*)d_in[0];
    const float* eig  = (const float*)d_in[1];
    const float* sr   = (const float*)d_in[2];
    const float* si   = (const float*)d_in[3];
    const float* filt = (const float*)d_in[4];
    const float* W1   = (const float*)d_in[5];
    const float* W2   = (const float*)d_in[6];
    const float* fs   = (const float*)d_in[7];
    float* out = (float*)d_out;

    // Scratch carved from d_out (134MB; fully overwritten by k_back last):
    //   WP: 1024 x KD = 16MB of chunk partials, then Xr/Xi/y1r/y1i (1MB each).
    float* WP  = out;
    float* Xr  = out + WPF;
    float* Xi  = Xr + (size_t)G * KD;
    float* y1r = Xi + (size_t)G * KD;
    float* y1i = y1r + (size_t)G * KD;
    // z is read by k_back while it writes d_out -> lives in ws.
    float* z   = (float*)d_ws;

    k_project<<<G * NCHUNK, 256, 0, stream>>>(x, eig, WP);
    k_reduce<<<G * 4, 256, 0, stream>>>(WP, filt, sr, si, Xr, Xi);
    k_mlp<1><<<G * 8, 256, 0, stream>>>(Xr, Xi, W1, nullptr, y1r, y1i);
    k_mlp<2><<<G * 8, 256, 0, stream>>>(y1r, y1i, W2, fs, z, nullptr);
    k_back<<<G * NCHUNK, 256, 0, stream>>>(x, eig, z, out);
}